// Round 5
// baseline (74.108 us; speedup 1.0000x reference)
//
#include <hip/hip_runtime.h>
#include <math.h>

constexpr int BN  = 8192;   // batch
constexpr int CN  = 4096;   // classes
constexpr int NT  = 512;    // threads per block (8 waves)
constexpr int NW  = NT / 64;
constexpr int EPT = CN / NT;   // 8 scalar elements per thread
constexpr int V4  = EPT / 4;   // 2 float4 per thread

// One block per batch row.
//   ws[b]      = sum_j log2_pijk  (sc partial, negative)
//   ws[BN + b] = -logp[b, target[b]]  (ce per-row term)
__global__ __launch_bounds__(NT) void sc_row_kernel(
    const float* __restrict__ x,
    const int*   __restrict__ target,
    const int*   __restrict__ distance_rank,
    const int*   __restrict__ k_idx,
    float*       __restrict__ ws)
{
    __shared__ float xs[CN];
    __shared__ int   rk[CN];
    __shared__ float red_m[NW], red_s[NW], red_a[NW];

    const int b    = blockIdx.x;
    const int tid  = threadIdx.x;
    const int lane = tid & 63;
    const int wave = tid >> 6;

    const int t = target[b];                      // s_load, issues immediately
    const float* __restrict__ xrow = x + (size_t)b * CN;
    const int*   __restrict__ drow = distance_rank + (size_t)t * CN;
    const int*   __restrict__ krow = k_idx + (size_t)b * (CN - 3);

    // ---- prefetch k indices to registers (independent of target)
    int kkv[EPT];
    #pragma unroll
    for (int i = 0; i < EPT; ++i) {
        const int j = tid + i * NT;
        kkv[i] = (j < CN - 3) ? krow[j] : 1;
    }

    // ---- stage x row (via regs, kept for online softmax) + rank row to LDS
    float4 xv[V4];
    #pragma unroll
    for (int i = 0; i < V4; ++i) {
        xv[i] = reinterpret_cast<const float4*>(xrow)[tid + i * NT];
        reinterpret_cast<float4*>(xs)[tid + i * NT] = xv[i];
        reinterpret_cast<int4*>(rk)[tid + i * NT] =
            reinterpret_cast<const int4*>(drow)[tid + i * NT];
    }

    // ---- online softmax on the register copies (no LDS re-read)
    float ml = -__builtin_huge_valf();
    #pragma unroll
    for (int i = 0; i < V4; ++i) {
        ml = fmaxf(ml, fmaxf(fmaxf(xv[i].x, xv[i].y), fmaxf(xv[i].z, xv[i].w)));
    }
    float sl = 0.f;
    #pragma unroll
    for (int i = 0; i < V4; ++i) {
        sl += __expf(xv[i].x - ml) + __expf(xv[i].y - ml)
            + __expf(xv[i].z - ml) + __expf(xv[i].w - ml);
    }
    #pragma unroll
    for (int off = 32; off; off >>= 1) {
        const float mo = __shfl_down(ml, off, 64);
        const float so = __shfl_down(sl, off, 64);
        const float mn = fmaxf(ml, mo);
        sl = sl * __expf(ml - mn) + so * __expf(mo - mn);
        ml = mn;
    }
    if (lane == 0) { red_m[wave] = ml; red_s[wave] = sl; }

    __syncthreads();   // xs + rk staged, per-wave (m,s) visible

    // cross-wave softmax merge (redundant per thread, barrier-free)
    float mg = red_m[0];
    #pragma unroll
    for (int w = 1; w < NW; ++w) mg = fmaxf(mg, red_m[w]);
    float sg = 0.f;
    #pragma unroll
    for (int w = 0; w < NW; ++w) sg += red_s[w] * __expf(red_m[w] - mg);

    if (tid == 0) ws[BN + b] = __logf(sg) + mg - xs[t];   // -logp[target]

    // ---- sc term, log2 space, gathering directly through rk -> xs:
    // yj = xs[rk[2+j]], yk = xs[rk[kk]]
    // D = e*(log2(a+dk^2) - log2(a+dj^2)); log2_pijk = -(max(D,0)+log2(1+2^-|D|))
    const float yi    = xs[rk[1]];
    const float alpha = (float)(CN - 1);
    const float e     = -0.5f * (float)CN;

    // issue all index gathers first (ILP), then value gathers, then math
    int cj[EPT], ck[EPT];
    #pragma unroll
    for (int i = 0; i < EPT; ++i) {
        const int j = tid + i * NT;
        const int jj = (j < CN - 3) ? j : 0;
        cj[i] = rk[2 + jj];       // contiguous LDS read
        ck[i] = rk[kkv[i]];       // random LDS gather
    }
    float acc = 0.f;
    #pragma unroll
    for (int i = 0; i < EPT; ++i) {
        const int j = tid + i * NT;
        const float yj = xs[cj[i]];   // random LDS gather
        const float yk = xs[ck[i]];   // random LDS gather
        const float dj = yi - yj;
        const float dk = yi - yk;
        const float Lj = __log2f(fmaf(dj, dj, alpha));
        const float Lk = __log2f(fmaf(dk, dk, alpha));
        const float D  = e * (Lk - Lj);
        const float term = fmaxf(D, 0.f) + __log2f(1.0f + __builtin_amdgcn_exp2f(-fabsf(D)));
        acc -= (j < CN - 3) ? term : 0.f;
    }

    #pragma unroll
    for (int off = 32; off; off >>= 1) acc += __shfl_down(acc, off, 64);
    if (lane == 0) red_a[wave] = acc;
    __syncthreads();
    if (tid == 0) {
        float a0 = red_a[0];
        #pragma unroll
        for (int w = 1; w < NW; ++w) a0 += red_a[w];
        ws[b] = a0;
    }
}

// Deterministic final reduction of the 2*BN partials, double accumulation.
__global__ __launch_bounds__(256) void sc_finalize(
    const float* __restrict__ ws, float* __restrict__ out)
{
    __shared__ double dred[8];
    const int tid  = threadIdx.x;
    const int lane = tid & 63;
    const int wave = tid >> 6;

    double sc = 0.0, ce = 0.0;
    for (int i = tid; i < BN; i += 256) {
        sc += (double)ws[i];
        ce += (double)ws[BN + i];
    }
    for (int off = 32; off; off >>= 1) {
        sc += __shfl_down(sc, off, 64);
        ce += __shfl_down(ce, off, 64);
    }
    if (lane == 0) { dred[wave] = sc; dred[4 + wave] = ce; }
    __syncthreads();
    if (tid == 0) {
        double scs = dred[0] + dred[1] + dred[2] + dred[3];
        double ces = dred[4] + dred[5] + dred[6] + dred[7];
        double ce_mean = ces / (double)BN;
        double sc_val  = -scs / (double)BN / (double)(CN - 1);
        out[0] = (float)(0.6 * ce_mean + 0.4 * sc_val);
    }
}

extern "C" void kernel_launch(void* const* d_in, const int* in_sizes, int n_in,
                              void* d_out, int out_size, void* d_ws, size_t ws_size,
                              hipStream_t stream) {
    const float* x             = (const float*)d_in[0];
    const int*   target        = (const int*)d_in[1];
    const int*   distance_rank = (const int*)d_in[2];
    const int*   k_idx         = (const int*)d_in[3];
    float*       ws            = (float*)d_ws;

    sc_row_kernel<<<BN, NT, 0, stream>>>(x, target, distance_rank, k_idx, ws);
    sc_finalize<<<1, 256, 0, stream>>>(ws, (float*)d_out);
}

// Round 6
// 72.896 us; speedup vs baseline: 1.0166x; 1.0166x over previous
//
#include <hip/hip_runtime.h>
#include <math.h>

constexpr int BN  = 8192;   // batch
constexpr int CN  = 4096;   // classes
constexpr int NT  = 512;    // threads per block (8 waves)
constexpr int NW  = NT / 64;
constexpr int EPT = CN / NT;   // 8 scalar elements per thread
constexpr int V4  = EPT / 4;   // 2 float4 per thread

// One block per batch row.
//   ws[b]      = sum_j log2_pijk  (sc partial, negative)
//   ws[BN + b] = -logp[b, target[b]]  (ce per-row term)
__global__ __launch_bounds__(NT) void sc_row_kernel(
    const float* __restrict__ x,
    const int*   __restrict__ target,
    const int*   __restrict__ distance_rank,
    const int*   __restrict__ k_idx,
    float*       __restrict__ ws)
{
    __shared__ float xs[CN];
    __shared__ float Lp[CN];          // Lp[c] = log2(alpha + (yi - xs[rk[c]])^2)
    __shared__ float red_m[NW], red_s[NW], red_a[NW];

    const int b    = blockIdx.x;
    const int tid  = threadIdx.x;
    const int lane = tid & 63;
    const int wave = tid >> 6;

    const int t = target[b];
    const float* __restrict__ xrow = x + (size_t)b * CN;
    const int*   __restrict__ drow = distance_rank + (size_t)t * CN;
    const int*   __restrict__ krow = k_idx + (size_t)b * (CN - 3);

    // ---- prefetch k indices + rank entries to registers (coalesced strided)
    int kkv[EPT];
    #pragma unroll
    for (int i = 0; i < EPT; ++i) {
        const int j = tid + i * NT;
        kkv[i] = (j < CN - 3) ? krow[j] : 3;
    }
    int rkv[EPT];
    #pragma unroll
    for (int i = 0; i < EPT; ++i) rkv[i] = drow[tid + i * NT];
    const int rk1 = drow[1];          // same addr all threads: broadcast via cache

    // ---- stage x row to LDS via registers (kept for online softmax)
    float4 xv[V4];
    #pragma unroll
    for (int i = 0; i < V4; ++i) {
        xv[i] = reinterpret_cast<const float4*>(xrow)[tid + i * NT];
        reinterpret_cast<float4*>(xs)[tid + i * NT] = xv[i];
    }

    // ---- online softmax on the register copies (no LDS re-read)
    float ml = -__builtin_huge_valf();
    #pragma unroll
    for (int i = 0; i < V4; ++i) {
        ml = fmaxf(ml, fmaxf(fmaxf(xv[i].x, xv[i].y), fmaxf(xv[i].z, xv[i].w)));
    }
    float sl = 0.f;
    #pragma unroll
    for (int i = 0; i < V4; ++i) {
        sl += __expf(xv[i].x - ml) + __expf(xv[i].y - ml)
            + __expf(xv[i].z - ml) + __expf(xv[i].w - ml);
    }
    #pragma unroll
    for (int off = 32; off; off >>= 1) {
        const float mo = __shfl_down(ml, off, 64);
        const float so = __shfl_down(sl, off, 64);
        const float mn = fmaxf(ml, mo);
        sl = sl * __expf(ml - mn) + so * __expf(mo - mn);
        ml = mn;
    }
    if (lane == 0) { red_m[wave] = ml; red_s[wave] = sl; }

    __syncthreads();   // xs staged, per-wave (m,s) visible

    // cross-wave softmax merge (redundant per thread, barrier-free)
    float mg = red_m[0];
    #pragma unroll
    for (int w = 1; w < NW; ++w) mg = fmaxf(mg, red_m[w]);
    float sg = 0.f;
    #pragma unroll
    for (int w = 0; w < NW; ++w) sg += red_s[w] * __expf(red_m[w] - mg);

    if (tid == 0) ws[BN + b] = __logf(sg) + mg - xs[t];   // -logp[target]

    // ---- transform: Lp[c] = log2(alpha + (yi - xs[rk[c]])^2)   (log hoisted
    //      out of the j-loop; evaluated once per rank position)
    const float yi    = xs[rk1];
    const float alpha = (float)(CN - 1);
    const float e     = -0.5f * (float)CN;
    #pragma unroll
    for (int i = 0; i < EPT; ++i) {
        const int   c = tid + i * NT;
        const float y = xs[rkv[i]];                 // random LDS gather
        const float d = yi - y;
        Lp[c] = __log2f(fmaf(d, d, alpha));         // strided b32 store, conflict-free
    }
    __syncthreads();   // Lp ready

    // ---- sc term:  D = e*(Lp[kk] - Lp[2+j]);
    //      log2_pijk = -(max(D,0) + log2(1 + 2^-|D|))
    float acc = 0.f;
    #pragma unroll
    for (int i = 0; i < EPT; ++i) {
        const int j = tid + i * NT;
        const float Lj = Lp[(j < CN - 3) ? (2 + j) : 0];  // stride-1, conflict-free
        const float Lk = Lp[kkv[i]];                      // single random gather
        const float D  = e * (Lk - Lj);
        const float term = fmaxf(D, 0.f)
                         + __log2f(1.0f + __builtin_amdgcn_exp2f(-fabsf(D)));
        acc -= (j < CN - 3) ? term : 0.f;
    }

    #pragma unroll
    for (int off = 32; off; off >>= 1) acc += __shfl_down(acc, off, 64);
    if (lane == 0) red_a[wave] = acc;
    __syncthreads();
    if (tid == 0) {
        float a0 = red_a[0];
        #pragma unroll
        for (int w = 1; w < NW; ++w) a0 += red_a[w];
        ws[b] = a0;
    }
}

// Deterministic final reduction of the 2*BN partials, double accumulation.
__global__ __launch_bounds__(256) void sc_finalize(
    const float* __restrict__ ws, float* __restrict__ out)
{
    __shared__ double dred[8];
    const int tid  = threadIdx.x;
    const int lane = tid & 63;
    const int wave = tid >> 6;

    double sc = 0.0, ce = 0.0;
    for (int i = tid; i < BN; i += 256) {
        sc += (double)ws[i];
        ce += (double)ws[BN + i];
    }
    for (int off = 32; off; off >>= 1) {
        sc += __shfl_down(sc, off, 64);
        ce += __shfl_down(ce, off, 64);
    }
    if (lane == 0) { dred[wave] = sc; dred[4 + wave] = ce; }
    __syncthreads();
    if (tid == 0) {
        double scs = dred[0] + dred[1] + dred[2] + dred[3];
        double ces = dred[4] + dred[5] + dred[6] + dred[7];
        double ce_mean = ces / (double)BN;
        double sc_val  = -scs / (double)BN / (double)(CN - 1);
        out[0] = (float)(0.6 * ce_mean + 0.4 * sc_val);
    }
}

extern "C" void kernel_launch(void* const* d_in, const int* in_sizes, int n_in,
                              void* d_out, int out_size, void* d_ws, size_t ws_size,
                              hipStream_t stream) {
    const float* x             = (const float*)d_in[0];
    const int*   target        = (const int*)d_in[1];
    const int*   distance_rank = (const int*)d_in[2];
    const int*   k_idx         = (const int*)d_in[3];
    float*       ws            = (float*)d_ws;

    sc_row_kernel<<<BN, NT, 0, stream>>>(x, target, distance_rank, k_idx, ws);
    sc_finalize<<<1, 256, 0, stream>>>(ws, (float*)d_out);
}

// Round 7
// 67.986 us; speedup vs baseline: 1.0900x; 1.0722x over previous
//
#include <hip/hip_runtime.h>
#include <math.h>

constexpr int BN  = 8192;   // batch
constexpr int CN  = 4096;   // classes
constexpr int NT  = 256;    // threads per block (4 waves) -> 8 blocks/CU
constexpr int NW  = NT / 64;
constexpr int EPT = CN / NT;   // 16 scalar elements per thread
constexpr int V4  = EPT / 4;   // 4 float4 per thread

// One block per batch row. xs is overwritten in place by Lp after the gather
// phase, halving LDS so 8 blocks co-reside per CU (32 waves).
//   ws[b]      = sum_j log2_pijk  (sc partial, negative)
//   ws[BN + b] = -logp[b, target[b]]  (ce per-row term)
__global__ __launch_bounds__(NT) void sc_row_kernel(
    const float* __restrict__ x,
    const int*   __restrict__ target,
    const int*   __restrict__ distance_rank,
    const int*   __restrict__ k_idx,
    float*       __restrict__ ws)
{
    __shared__ float xs[CN];          // phase 1-2: x row; phase 3+: Lp values
    __shared__ float red_m[NW], red_s[NW], red_a[NW];

    const int b    = blockIdx.x;
    const int tid  = threadIdx.x;
    const int lane = tid & 63;
    const int wave = tid >> 6;

    const int t = target[b];
    const float* __restrict__ xrow = x + (size_t)b * CN;
    const int*   __restrict__ drow = distance_rank + (size_t)t * CN;
    const int*   __restrict__ krow = k_idx + (size_t)b * (CN - 3);

    // ---- entry loads: rank entries to registers, x row staged to LDS
    int rkv[EPT];
    #pragma unroll
    for (int i = 0; i < EPT; ++i) rkv[i] = drow[tid + i * NT];
    const int rk1 = drow[1];          // broadcast (same addr all threads)

    float4 xv[V4];
    #pragma unroll
    for (int i = 0; i < V4; ++i) {
        xv[i] = reinterpret_cast<const float4*>(xrow)[tid + i * NT];
        reinterpret_cast<float4*>(xs)[tid + i * NT] = xv[i];
    }

    // ---- online softmax on register copies
    float ml = -__builtin_huge_valf();
    #pragma unroll
    for (int i = 0; i < V4; ++i) {
        ml = fmaxf(ml, fmaxf(fmaxf(xv[i].x, xv[i].y), fmaxf(xv[i].z, xv[i].w)));
    }
    float sl = 0.f;
    #pragma unroll
    for (int i = 0; i < V4; ++i) {
        sl += __expf(xv[i].x - ml) + __expf(xv[i].y - ml)
            + __expf(xv[i].z - ml) + __expf(xv[i].w - ml);
    }
    #pragma unroll
    for (int off = 32; off; off >>= 1) {
        const float mo = __shfl_down(ml, off, 64);
        const float so = __shfl_down(sl, off, 64);
        const float mn = fmaxf(ml, mo);
        sl = sl * __expf(ml - mn) + so * __expf(mo - mn);
        ml = mn;
    }
    if (lane == 0) { red_m[wave] = ml; red_s[wave] = sl; }

    __syncthreads();   // B1: xs staged, per-wave (m,s) visible

    float mg = red_m[0];
    #pragma unroll
    for (int w = 1; w < NW; ++w) mg = fmaxf(mg, red_m[w]);
    float sg = 0.f;
    #pragma unroll
    for (int w = 0; w < NW; ++w) sg += red_s[w] * __expf(red_m[w] - mg);

    if (tid == 0) ws[BN + b] = __logf(sg) + mg - xs[t];   // -logp[target]

    // ---- gather phase: all xs reads complete before overwrite
    const float yi = xs[rk1];
    float yv[EPT];
    #pragma unroll
    for (int i = 0; i < EPT; ++i) yv[i] = xs[rkv[i]];     // random LDS gather

    __syncthreads();   // B2: every thread done reading xs

    // ---- in-place transform: xs[c] <- Lp[c] = log2(alpha + (yi - y_c)^2);
    //      k indices prefetched here (in flight across B3)
    const float alpha = (float)(CN - 1);
    const float e     = -0.5f * (float)CN;
    int kkv[EPT];
    #pragma unroll
    for (int i = 0; i < EPT; ++i) {
        const int c = tid + i * NT;
        const float d = yi - yv[i];
        xs[c] = __log2f(fmaf(d, d, alpha));               // conflict-free store
        kkv[i] = (c < CN - 3) ? krow[c] : 3;
    }
    __syncthreads();   // B3: Lp ready

    // ---- sc term:  D = e*(Lp[kk] - Lp[2+j]);
    //      log2_pijk = -(max(D,0) + log2(1 + 2^-|D|))
    float acc = 0.f;
    #pragma unroll
    for (int i = 0; i < EPT; ++i) {
        const int j = tid + i * NT;
        const float Lj = xs[(j < CN - 3) ? (2 + j) : 0];  // stride-1 read
        const float Lk = xs[kkv[i]];                      // single random gather
        const float D  = e * (Lk - Lj);
        const float term = fmaxf(D, 0.f)
                         + __log2f(1.0f + __builtin_amdgcn_exp2f(-fabsf(D)));
        acc -= (j < CN - 3) ? term : 0.f;
    }

    #pragma unroll
    for (int off = 32; off; off >>= 1) acc += __shfl_down(acc, off, 64);
    if (lane == 0) red_a[wave] = acc;
    __syncthreads();
    if (tid == 0) {
        float a0 = red_a[0];
        #pragma unroll
        for (int w = 1; w < NW; ++w) a0 += red_a[w];
        ws[b] = a0;
    }
}

// Deterministic final reduction of the 2*BN partials, double accumulation.
__global__ __launch_bounds__(1024) void sc_finalize(
    const float* __restrict__ ws, float* __restrict__ out)
{
    __shared__ double dred[32];
    const int tid  = threadIdx.x;
    const int lane = tid & 63;
    const int wave = tid >> 6;

    double sc = 0.0, ce = 0.0;
    for (int i = tid; i < BN; i += 1024) {
        sc += (double)ws[i];
        ce += (double)ws[BN + i];
    }
    for (int off = 32; off; off >>= 1) {
        sc += __shfl_down(sc, off, 64);
        ce += __shfl_down(ce, off, 64);
    }
    if (lane == 0) { dred[wave] = sc; dred[16 + wave] = ce; }
    __syncthreads();
    if (tid == 0) {
        double scs = 0.0, ces = 0.0;
        #pragma unroll
        for (int w = 0; w < 16; ++w) { scs += dred[w]; ces += dred[16 + w]; }
        double ce_mean = ces / (double)BN;
        double sc_val  = -scs / (double)BN / (double)(CN - 1);
        out[0] = (float)(0.6 * ce_mean + 0.4 * sc_val);
    }
}

extern "C" void kernel_launch(void* const* d_in, const int* in_sizes, int n_in,
                              void* d_out, int out_size, void* d_ws, size_t ws_size,
                              hipStream_t stream) {
    const float* x             = (const float*)d_in[0];
    const int*   target        = (const int*)d_in[1];
    const int*   distance_rank = (const int*)d_in[2];
    const int*   k_idx         = (const int*)d_in[3];
    float*       ws            = (float*)d_ws;

    sc_row_kernel<<<BN, NT, 0, stream>>>(x, target, distance_rank, k_idx, ws);
    sc_finalize<<<1, 1024, 0, stream>>>(ws, (float*)d_out);
}